// Round 10
// baseline (166.403 us; speedup 1.0000x reference)
//
#include <hip/hip_runtime.h>

// MoE: out[b,:] = sum_e softmax(gate(x))[b,e] * (W3_e^T @ relu(W2_e^T @ relu(W1_e^T @ x_b + b1) + b2) + b3)
// Tokens-as-N MFMA, 16x16 shapes (R8 structure, HW-verified). L1: 16x16x16 (K=7 useful, k=4q+j).
// L2/L3/gate-L2: 16x16x32 with K-permutation pi(q*8+j)=q*4+(j&3)+16*(j>>2) so C/D layout ==
// next layer's B layout in-lane. 2 experts/wave, 4-wave blocks.
// R10: DUAL-TILE ILP. R9 counters (CU-level SQ semantics) show true per-SIMD utilization ~13%:
//     latency-bound on one serial chain/wave at ~2-3 resident waves/SIMD. Occupancy pushes
//     failed twice -> double ILP instead: each wave runs TWO independent tile chains
//     (shared weights ~56 regs + 2x temps ~65 = ~120 < 128, no spill), barrier per 2 tiles,
//     combine uses lanes 0-31 of wave0 (lanes 16-31 take tile B).

typedef _Float16 half2_t __attribute__((ext_vector_type(2)));
typedef _Float16 half4_t __attribute__((ext_vector_type(4)));
typedef _Float16 half8_t __attribute__((ext_vector_type(8)));
typedef __fp16   fp16v2  __attribute__((ext_vector_type(2)));
typedef float  float4_t __attribute__((ext_vector_type(4)));
typedef float  float2_t __attribute__((ext_vector_type(2)));
typedef int    int2_t   __attribute__((ext_vector_type(2)));
typedef int    int4_t   __attribute__((ext_vector_type(4)));

#define MFMA_K32(A, B, C) __builtin_amdgcn_mfma_f32_16x16x32_f16((A), (B), (C), 0, 0, 0)
#define MFMA_K16(A, B, C) __builtin_amdgcn_mfma_f32_16x16x16f16((A), (B), (C), 0, 0, 0)

static constexpr int E_ = 8, DIN_ = 6, H_ = 32, EPW_ = 2;

union H8U { half2_t h2[4]; half8_t h8; int4_t i4; };
union H4U { half2_t h2[2]; half4_t h4; int2_t i2; };
union HI  { half2_t h; int i; };
union PKU { fp16v2 p; half2_t h; };
union FI  { float f; int i; };

__device__ __forceinline__ half2_t pkrtz(float a, float b) {
    PKU u; u.p = __builtin_amdgcn_cvt_pkrtz(a, b);
    return u.h;
}

__device__ __forceinline__ half2_t relu2(half2_t v) {
    const half2_t z = {(_Float16)0.0f, (_Float16)0.0f};
    return __builtin_elementwise_max(v, z);
}

__device__ __forceinline__ float bperm_f(int addr, float v) {
    FI u; u.f = v;
    u.i = __builtin_amdgcn_ds_bpermute(addr, u.i);
    return u.f;
}

__global__ __launch_bounds__(256)
void moe_kernel(
    const float* __restrict__ x,  const float* __restrict__ W1, const float* __restrict__ b1,
    const float* __restrict__ W2, const float* __restrict__ b2, const float* __restrict__ W3,
    const float* __restrict__ b3, const float* __restrict__ Wg1, const float* __restrict__ bg1,
    const float* __restrict__ Wg2, const float* __restrict__ bg2,
    float* __restrict__ out, int nTiles, int tilesPerBlock)
{
    const int tid  = threadIdx.x;
    const int lane = tid & 63;
    const int t    = lane & 15;   // token slot
    const int q    = lane >> 4;   // K-quad
    const int wv   = tid >> 6;    // wave in block: 0..3
    const int eb   = wv * EPW_;   // this wave's expert base

    __shared__ float2_t cbuf[2][2][4][16];   // [iterParity][tileSel][wave][token], 2 KB

    const float L2E = 1.44269504f;

    // ---- gate L1 A-fragments (K=16, k=4q+j; slots 0..5 = x features, 6 = bias-as-1.0)
    H4U G1[2];
    #pragma unroll
    for (int f = 0; f < 2; ++f) {
        float v0 = 0.f, v1 = 0.f, v2 = 0.f, v3 = 0.f;
        if (q == 0) {
            v0 = Wg1[0 * H_ + f * 16 + t]; v1 = Wg1[1 * H_ + f * 16 + t];
            v2 = Wg1[2 * H_ + f * 16 + t]; v3 = Wg1[3 * H_ + f * 16 + t];
        } else if (q == 1) {
            v0 = Wg1[4 * H_ + f * 16 + t]; v1 = Wg1[5 * H_ + f * 16 + t];
            v2 = bg1[f * 16 + t];          v3 = 0.f;
        }
        G1[f].h2[0] = pkrtz(v0, v1); G1[f].h2[1] = pkrtz(v2, v3);
    }
    // ---- gate L2 A-fragment (K=32, pi layout), pre-scaled by log2(e)
    H8U G2;
    #pragma unroll
    for (int p = 0; p < 4; ++p) {
        int c0 = ((p >> 1) << 4) + q * 4 + ((p & 1) << 1);
        float v0 = (t < E_) ? Wg2[c0 * E_ + t] * L2E : 0.f;
        float v1 = (t < E_) ? Wg2[(c0 + 1) * E_ + t] * L2E : 0.f;
        G2.h2[p] = pkrtz(v0, v1);
    }

    // ---- this wave's 2 experts: L1 (K16), L2 (K32 pi), L3 (K32 pi, block-diag), b2 pairs
    H4U W1F[EPW_][2];
    H8U W2F[EPW_][2], W3F[EPW_], B2R[EPW_];
    #pragma unroll
    for (int j = 0; j < EPW_; ++j) {
        const int e = eb + j;
        #pragma unroll
        for (int f = 0; f < 2; ++f) {
            float v0 = 0.f, v1 = 0.f, v2 = 0.f, v3 = 0.f;
            const float* We = W1 + (size_t)e * DIN_ * H_ + f * 16 + t;
            if (q == 0)      { v0 = We[0 * H_]; v1 = We[1 * H_]; v2 = We[2 * H_]; v3 = We[3 * H_]; }
            else if (q == 1) { v0 = We[4 * H_]; v1 = We[5 * H_]; v2 = b1[e * H_ + f * 16 + t]; }
            W1F[j][f].h2[0] = pkrtz(v0, v1); W1F[j][f].h2[1] = pkrtz(v2, v3);
        }
        #pragma unroll
        for (int p = 0; p < 4; ++p) {
            int c0 = ((p >> 1) << 4) + q * 4 + ((p & 1) << 1);
            W2F[j][0].h2[p] = pkrtz(W2[(e * H_ + c0) * H_ + 0  + t], W2[(e * H_ + c0 + 1) * H_ + 0  + t]);
            W2F[j][1].h2[p] = pkrtz(W2[(e * H_ + c0) * H_ + 16 + t], W2[(e * H_ + c0 + 1) * H_ + 16 + t]);
            B2R[j].h2[p]    = pkrtz(b2[e * H_ + c0], b2[e * H_ + c0 + 1]);
            float v0 = 0.f, v1 = 0.f;
            if ((t >> 1) == e) {
                v0 = W3[(e * H_ + c0) * 2 + (t & 1)];
                v1 = W3[(e * H_ + c0 + 1) * 2 + (t & 1)];
            }
            W3F[j].h2[p] = pkrtz(v0, v1);
        }
    }

    // ---- persistent C-inits: bg2 (log2 domain); b3 rows m=4wv+r == this wave's (e,o) rows
    float4_t bg2F, b3F;
    #pragma unroll
    for (int r = 0; r < 4; ++r) {
        int m = q * 4 + r;
        bg2F[r] = (m < E_) ? bg2[m] * L2E : 0.f;
        b3F[r]  = b3[m];
    }
    const float4_t zero4 = {0.f, 0.f, 0.f, 0.f};

    const int gsrc = ((((q >> 1) << 4) | t) << 2);   // gate distribute pull
    const int csrc = (((wv << 4) | t) << 2);         // combine pull (quad wv)

    const int tile0 = blockIdx.x * tilesPerBlock;

    // per-lane x source offsets (quads>=2 values never consumed: A-frags zero at k>=8)
    const int xo1 = (q == 0) ? 0 : 4;
    const int xo2 = (q == 0) ? 2 : 4;
    const float* xq = x + ((size_t)tile0 * 16 + t) * DIN_;
    const int strideT = 16 * DIN_;   // floats per tile

    float2_t laA = {0.f,0.f}, lbA = {0.f,0.f}, laB = {0.f,0.f}, lbB = {0.f,0.f};
    if (tile0 < nTiles)     { laA = *(const float2_t*)(xq + xo1);           lbA = *(const float2_t*)(xq + xo2); }
    if (tile0 + 1 < nTiles) { laB = *(const float2_t*)(xq + strideT + xo1); lbB = *(const float2_t*)(xq + strideT + xo2); }

    HI onei; onei.h = pkrtz(1.f, 0.f);
    const bool isq0 = (q == 0);

    for (int it = 0; it < tilesPerBlock; it += 2) {
        const int tA = tile0 + it;
        if (tA >= nTiles) break;             // uniform across block
        const int  tB   = tA + 1;
        const bool hasB = (tB < nTiles);

        // ---- x B-fragments for both tiles
        H4U uxA, uxB;
        {
            uxA.h2[0] = pkrtz(laA[0], laA[1]);
            HI hb; hb.h = pkrtz(lbA[0], lbA[1]);
            HI se; se.i = isq0 ? hb.i : onei.i;
            uxA.h2[1] = se.h;
            uxB.h2[0] = pkrtz(laB[0], laB[1]);
            HI hb2; hb2.h = pkrtz(lbB[0], lbB[1]);
            HI se2; se2.i = isq0 ? hb2.i : onei.i;
            uxB.h2[1] = se2.h;
        }
        const half4_t xBA = uxA.h4;
        const half4_t xBB = uxB.h4;

        // ---- prefetch next pair
        if ((it + 2) < tilesPerBlock) {
            const float* xn = xq + (size_t)(it + 2) * strideT;
            if (tA + 2 < nTiles) { laA = *(const float2_t*)(xn + xo1);           lbA = *(const float2_t*)(xn + xo2); }
            if (tA + 3 < nTiles) { laB = *(const float2_t*)(xn + strideT + xo1); lbB = *(const float2_t*)(xn + strideT + xo2); }
        }

        // ---- gates (two independent chains; scheduler interleaves)
        float4_t glA, glB;
        {
            float4_t hgLo = MFMA_K16(G1[0].h4, xBA, zero4);
            float4_t hgHi = MFMA_K16(G1[1].h4, xBA, zero4);
            float4_t hgLo2 = MFMA_K16(G1[0].h4, xBB, zero4);
            float4_t hgHi2 = MFMA_K16(G1[1].h4, xBB, zero4);
            H8U uh, uh2;
            uh.h2[0] = relu2(pkrtz(hgLo[0], hgLo[1]));
            uh.h2[1] = relu2(pkrtz(hgLo[2], hgLo[3]));
            uh.h2[2] = relu2(pkrtz(hgHi[0], hgHi[1]));
            uh.h2[3] = relu2(pkrtz(hgHi[2], hgHi[3]));
            uh2.h2[0] = relu2(pkrtz(hgLo2[0], hgLo2[1]));
            uh2.h2[1] = relu2(pkrtz(hgLo2[2], hgLo2[3]));
            uh2.h2[2] = relu2(pkrtz(hgHi2[0], hgHi2[1]));
            uh2.h2[3] = relu2(pkrtz(hgHi2[2], hgHi2[3]));
            glA = MFMA_K32(G2.h8, uh.h8, bg2F);
            glB = MFMA_K32(G2.h8, uh2.h8, bg2F);
        }

        // ---- softmax (both tiles), normalization deferred
        float exA0 = __builtin_amdgcn_exp2f(glA[0]);
        float exA1 = __builtin_amdgcn_exp2f(glA[1]);
        float exA2 = __builtin_amdgcn_exp2f(glA[2]);
        float exA3 = __builtin_amdgcn_exp2f(glA[3]);
        float exB0 = __builtin_amdgcn_exp2f(glB[0]);
        float exB1 = __builtin_amdgcn_exp2f(glB[1]);
        float exB2 = __builtin_amdgcn_exp2f(glB[2]);
        float exB3 = __builtin_amdgcn_exp2f(glB[3]);
        float sA = (exA0 + exA1) + (exA2 + exA3);
        float sB = (exB0 + exB1) + (exB2 + exB3);
        sA += __shfl_xor(sA, 16);
        sB += __shfl_xor(sB, 16);
        float rsA = __builtin_amdgcn_rcpf(sA);
        float rsB = __builtin_amdgcn_rcpf(sB);
        HI paA, pbA, paB, pbB;
        paA.h = pkrtz(exA0, exA1);  pbA.h = pkrtz(exA2, exA3);
        paB.h = pkrtz(exB0, exB1);  pbB.h = pkrtz(exB2, exB3);
        int vaA = __builtin_amdgcn_ds_bpermute(gsrc, paA.i);
        int vbA = __builtin_amdgcn_ds_bpermute(gsrc, pbA.i);
        int vaB = __builtin_amdgcn_ds_bpermute(gsrc, paB.i);
        int vbB = __builtin_amdgcn_ds_bpermute(gsrc, pbB.i);
        HI gsA; gsA.i = (q & 1) ? vbA : vaA;
        HI gsB; gsB.i = (q & 1) ? vbB : vaB;
        float gaA = (float)gsA.h[0], gbA = (float)gsA.h[1];
        float gaB = (float)gsB.h[0], gbB = (float)gsB.h[1];

        // ---- experts: interleaved A/B chains per expert
        float4_t YA = b3F, YB = b3F;
        #pragma unroll
        for (int j = 0; j < EPW_; ++j) {
            float4_t loA = MFMA_K16(W1F[j][0].h4, xBA, zero4);
            float4_t hiA = MFMA_K16(W1F[j][1].h4, xBA, zero4);
            float4_t loB = MFMA_K16(W1F[j][0].h4, xBB, zero4);
            float4_t hiB = MFMA_K16(W1F[j][1].h4, xBB, zero4);
            H8U u1A, u1B;
            u1A.h2[0] = relu2(pkrtz(loA[0], loA[1]));
            u1A.h2[1] = relu2(pkrtz(loA[2], loA[3]));
            u1A.h2[2] = relu2(pkrtz(hiA[0], hiA[1]));
            u1A.h2[3] = relu2(pkrtz(hiA[2], hiA[3]));
            u1B.h2[0] = relu2(pkrtz(loB[0], loB[1]));
            u1B.h2[1] = relu2(pkrtz(loB[2], loB[3]));
            u1B.h2[2] = relu2(pkrtz(hiB[0], hiB[1]));
            u1B.h2[3] = relu2(pkrtz(hiB[2], hiB[3]));
            float4_t lo2A = MFMA_K32(W2F[j][0].h8, u1A.h8, zero4);
            float4_t hi2A = MFMA_K32(W2F[j][1].h8, u1A.h8, zero4);
            float4_t lo2B = MFMA_K32(W2F[j][0].h8, u1B.h8, zero4);
            float4_t hi2B = MFMA_K32(W2F[j][1].h8, u1B.h8, zero4);
            H8U u2A, u2B;
            u2A.h2[0] = relu2(pkrtz(lo2A[0], lo2A[1]) + B2R[j].h2[0]);
            u2A.h2[1] = relu2(pkrtz(lo2A[2], lo2A[3]) + B2R[j].h2[1]);
            u2A.h2[2] = relu2(pkrtz(hi2A[0], hi2A[1]) + B2R[j].h2[2]);
            u2A.h2[3] = relu2(pkrtz(hi2A[2], hi2A[3]) + B2R[j].h2[3]);
            u2B.h2[0] = relu2(pkrtz(lo2B[0], lo2B[1]) + B2R[j].h2[0]);
            u2B.h2[1] = relu2(pkrtz(lo2B[2], lo2B[3]) + B2R[j].h2[1]);
            u2B.h2[2] = relu2(pkrtz(hi2B[0], hi2B[1]) + B2R[j].h2[2]);
            u2B.h2[3] = relu2(pkrtz(hi2B[2], hi2B[3]) + B2R[j].h2[3]);
            YA = MFMA_K32(W3F[j].h8, u2A.h8, YA);
            YB = MFMA_K32(W3F[j].h8, u2B.h8, YB);
        }

        // ---- gated partials; pull quad-wv rows to all lanes
        float pA0 = gaA * YA[0] + gbA * YA[2];
        float pA1 = gaA * YA[1] + gbA * YA[3];
        float pB0 = gaB * YB[0] + gbB * YB[2];
        float pB1 = gaB * YB[1] + gbB * YB[3];
        pA0 = bperm_f(csrc, pA0);
        pA1 = bperm_f(csrc, pA1);
        pB0 = bperm_f(csrc, pB0);
        pB1 = bperm_f(csrc, pB1);

        // ---- cross-wave combine: lanes 0-15 carry tile A, lanes 16-31 tile B
        const int par = (it >> 1) & 1;
        if (lane < 32) {
            const int sel = lane >> 4;
            float2_t o;
            o[0] = sel ? pB0 : pA0;
            o[1] = sel ? pB1 : pA1;
            cbuf[par][sel][wv][t] = o;
        }
        __syncthreads();
        if (wv == 0 && lane < 32) {
            const int sel = lane >> 4;
            if (sel == 0 || hasB) {
                float2_t o  = cbuf[par][sel][0][t];
                float2_t o1 = cbuf[par][sel][1][t];
                float2_t o2 = cbuf[par][sel][2][t];
                float2_t o3 = cbuf[par][sel][3][t];
                const float rss = sel ? rsB : rsA;
                const int   tt  = sel ? tB : tA;
                o[0] = (o[0] + o1[0] + o2[0] + o3[0]) * rss;
                o[1] = (o[1] + o1[1] + o2[1] + o3[1]) * rss;
                *(float2_t*)(out + ((size_t)tt * 16 + t) * 2) = o;
            }
        }
    }
}

extern "C" void kernel_launch(void* const* d_in, const int* in_sizes, int n_in,
                              void* d_out, int out_size, void* d_ws, size_t ws_size,
                              hipStream_t stream) {
    const float* x   = (const float*)d_in[0];
    const float* W1  = (const float*)d_in[1];
    const float* b1  = (const float*)d_in[2];
    const float* W2  = (const float*)d_in[3];
    const float* b2  = (const float*)d_in[4];
    const float* W3  = (const float*)d_in[5];
    const float* b3  = (const float*)d_in[6];
    const float* Wg1 = (const float*)d_in[7];
    const float* bg1 = (const float*)d_in[8];
    const float* Wg2 = (const float*)d_in[9];
    const float* bg2 = (const float*)d_in[10];
    float* out = (float*)d_out;

    const int B      = in_sizes[0] / DIN_;
    const int nTiles = (B + 15) / 16;
    const int blocks = 2048;                 // 32 tiles/block -> 16 dual-tile iterations
    const int tpb    = (nTiles + blocks - 1) / blocks;

    moe_kernel<<<blocks, 256, 0, stream>>>(x, W1, b1, W2, b2, W3, b3,
                                           Wg1, bg1, Wg2, bg2, out, nTiles, tpb);
}